// Round 4
// baseline (20450.031 us; speedup 1.0000x reference)
//
#include <hip/hip_runtime.h>
#include <hip/hip_bf16.h>

#define BB 16
#define NN 1024
#define BN (BB*NN)
#define KK 20

// monotone float <-> uint key for atomic max/min (handles negatives)
__device__ inline unsigned fkey(float x) {
    unsigned b = __float_as_uint(x);
    return (b & 0x80000000u) ? ~b : (b | 0x80000000u);
}
__device__ inline float funkey(unsigned k) {
    unsigned b = (k & 0x80000000u) ? (k ^ 0x80000000u) : ~k;
    return __uint_as_float(b);
}

// ============ cast pos -> double + row sqnorm ============
__global__ void k_cast3(const float* __restrict__ pos, double* __restrict__ xd,
                        double* __restrict__ sq) {
    int gn = blockIdx.x * blockDim.x + threadIdx.x;
    if (gn >= BN) return;
    double s = 0.0;
    #pragma unroll
    for (int c = 0; c < 3; ++c) {
        double v = (double)pos[gn * 3 + c];
        xd[gn * 3 + c] = v;
        s += v * v;
    }
    sq[gn] = s;
}

// ============ kNN v2: wave-per-row, register-resident distances ============
// Block = 256 threads = 4 waves = 4 query rows. Lane l holds distances for
// m = j*64 + l (j=0..15) in registers. Dot from LDS tile; selection is 20x
// (local argmin over 16 regs + wave butterfly argmin), no barriers.
// fp64 exact, +1e10 diagonal, lowest-index tie-break.
template<int C, int TM>
__global__ __launch_bounds__(256) void k_knn2(const double* __restrict__ x,
                                              const double* __restrict__ sq,
                                              int* __restrict__ idx) {
    const int ST = C + 1;                    // pad: bank stride 2 -> free 2-way
    const int SUB = 64 / TM;                 // 1 (C<=64) or 2 (C=128)
    __shared__ double xt[TM * ST];
    __shared__ double xn4[4 * C];
    __shared__ double sqs[NN];
    const int tid = threadIdx.x, lane = tid & 63, w = tid >> 6;
    const int b = blockIdx.y;
    const int n0 = blockIdx.x * 4;
    const int n = n0 + w;
    const double* xb = x + (size_t)b * NN * C;

    for (int t = tid; t < NN; t += 256) sqs[t] = sq[b * NN + t];
    for (int t = tid; t < 4 * C; t += 256) {
        int r = t / C, c = t - r * C;
        xn4[r * C + c] = xb[(size_t)(n0 + r) * C + c];
    }
    __syncthreads();
    const double sqn = sqs[n];

    double dloc[16];
    #pragma unroll
    for (int g = 0; g < 16; ++g) {
        #pragma unroll
        for (int s = 0; s < SUB; ++s) {
            const int m0 = g * 64 + s * TM;
            // load candidate tile
            for (int t = tid; t < TM * C; t += 256) {
                int r = t / C, c = t - r * C;
                xt[r * ST + c] = xb[(size_t)(m0 + r) * C + c];
            }
            __syncthreads();
            if (SUB == 1) {
                const double* xr = &xt[lane * ST];
                const double* xq = &xn4[w * C];
                double dot = 0.0;
                for (int c = 0; c < C; ++c) dot += xr[c] * xq[c];
                int m = m0 + lane;
                double dd = sqn + sqs[m] - 2.0 * dot;
                if (m == n) dd += 1e10;
                dloc[g] = dd;
            } else {
                const int half = lane >> 5;
                const double* xr = &xt[(lane & 31) * ST + half * (C / 2)];
                const double* xq = &xn4[w * C + half * (C / 2)];
                double part = 0.0;
                for (int c = 0; c < C / 2; ++c) part += xr[c] * xq[c];
                double dot = part + __shfl_xor(part, 32, 64);
                int m = m0 + (lane & 31);
                double dd = sqn + sqs[m] - 2.0 * dot;
                if (m == n) dd += 1e10;
                if (half == s) dloc[g] = dd;   // owner: lane == m & 63
            }
            __syncthreads();
        }
    }

    // ---- selection: 20x wave argmin with masking ----
    const size_t rowbase = (size_t)(b * NN + n) * KK;
    for (int it = 0; it < KK; ++it) {
        double bv = dloc[0]; int bj = 0;
        #pragma unroll
        for (int j = 1; j < 16; ++j)
            if (dloc[j] < bv) { bv = dloc[j]; bj = j; }
        int bm = bj * 64 + lane;
        #pragma unroll
        for (int off = 32; off > 0; off >>= 1) {
            double ov = __shfl_xor(bv, off, 64);
            int    om = __shfl_xor(bm, off, 64);
            if (ov < bv || (ov == bv && om < bm)) { bv = ov; bm = om; }
        }
        if (lane == 0) idx[rowbase + it] = bm;
        if ((bm & 63) == lane) {
            const int wj = bm >> 6;
            #pragma unroll
            for (int j = 0; j < 16; ++j)
                if (j == wj) dloc[j] = 1e300;
        }
    }
}

// ============ UV GEMM fp64, 64-column chunk ============
template<int C>
__global__ void k_uv_d(const double* __restrict__ x, const float* __restrict__ W,
                       const float* __restrict__ bias,
                       double* __restrict__ U, double* __restrict__ V,
                       int Cout, int c0) {
    __shared__ double xt[16 * C];
    const int tid = threadIdx.x;
    const int col = tid & 63;
    const int gcol = c0 + col;
    const int r4 = tid >> 6;
    const int row0 = blockIdx.x * 16;
    for (int t = tid; t < 16 * C; t += 256) xt[t] = x[(size_t)row0 * C + t];
    __syncthreads();
    double u[4] = {0,0,0,0}, v[4] = {0,0,0,0};
    for (int c = 0; c < C; ++c) {
        double wt = (double)W[(size_t)c * Cout + gcol];
        double wd = (double)W[(size_t)(C + c) * Cout + gcol] - wt;
        #pragma unroll
        for (int rr = 0; rr < 4; ++rr) {
            double xv = xt[(r4 * 4 + rr) * C + c];
            u[rr] += xv * wt;
            v[rr] += xv * wd;
        }
    }
    double bb = (double)bias[gcol];
    #pragma unroll
    for (int rr = 0; rr < 4; ++rr) {
        size_t o = (size_t)(row0 + r4 * 4 + rr) * 64 + col;
        U[o] = u[rr] + bb;
        V[o] = v[rr];
    }
}

// ============ gather fp64 (L1-3): max/min over k + BN stats ============
__global__ void k_gather_d(const int* __restrict__ idx,
                           double* __restrict__ U, const double* __restrict__ V,
                           double* __restrict__ Hmin,
                           double* __restrict__ ssum, double* __restrict__ sssq, int NB) {
    const int tid = threadIdx.x, CS = blockDim.x;
    __shared__ int lidx[KK];
    double accs = 0.0, accq = 0.0;
    const int gn0 = blockIdx.x * NB;
    for (int r = 0; r < NB; ++r) {
        int gn = gn0 + r;
        int b = gn >> 10;
        __syncthreads();
        if (tid < KK) lidx[tid] = idx[(size_t)gn * KK + tid];
        __syncthreads();
        double u = U[(size_t)gn * CS + tid];
        double vmax = -1e300, vmin = 1e300, vs = 0.0, vss = 0.0;
        for (int j = 0; j < KK; ++j) {
            int m = lidx[j];
            double vv = V[(size_t)((b << 10) + m) * CS + tid];
            vmax = fmax(vmax, vv);
            vmin = fmin(vmin, vv);
            vs  += vv;
            vss += vv * vv;
        }
        accs += (double)KK * u + vs;
        accq += (double)KK * u * u + 2.0 * u * vs + vss;
        U[(size_t)gn * CS + tid]    = u + vmax;
        Hmin[(size_t)gn * CS + tid] = u + vmin;
    }
    atomicAdd(&ssum[tid], accs);
    atomicAdd(&sssq[tid], accq);
}

// ============ BN finalize fp64 ============
__global__ void k_bnfin_d(const double* __restrict__ ssum, const double* __restrict__ sssq,
                          const float* __restrict__ g, const float* __restrict__ be,
                          double* __restrict__ S, double* __restrict__ T, int c0) {
    int gc = c0 + threadIdx.x;
    const double M = (double)BN * (double)KK;
    double mean = ssum[gc] / M;
    double var  = sssq[gc] / M - mean * mean;
    if (var < 0.0) var = 0.0;
    double s = (double)g[gc] / sqrt(var + 1e-5);
    double t = (double)be[gc] - mean * s;
    S[gc] = s; T[gc] = t;
}

// ============ apply fp64 chunk ============
__global__ void k_apply_d(const double* __restrict__ Hmax, const double* __restrict__ Hmin,
                          const double* __restrict__ S, const double* __restrict__ T,
                          double* __restrict__ y, int Cout, int c0) {
    const int gn = blockIdx.x, tid = threadIdx.x;
    double s = S[c0 + tid], t = T[c0 + tid];
    double h = (s >= 0.0) ? Hmax[(size_t)gn * 64 + tid] : Hmin[(size_t)gn * 64 + tid];
    y[(size_t)gn * Cout + c0 + tid] = fmax(s * h + t, 0.0);
}

// ============ row sqnorm fp64 ============
__global__ void k_sqnorm_d(const double* __restrict__ y, double* __restrict__ sq, int C) {
    const int row = blockIdx.x * 4 + (threadIdx.x >> 6);
    const int lane = threadIdx.x & 63;
    const double* yr = y + (size_t)row * C;
    double s = 0.0;
    for (int c = lane; c < C; c += 64) { double v = yr[c]; s += v * v; }
    for (int off = 32; off > 0; off >>= 1) s += __shfl_xor(s, off, 64);
    if (lane == 0) sq[row] = s;
}

// ============ layer-4 fp32: UV GEMM (CS=128 chunks) ============
__global__ void k_uv_f(const double* __restrict__ x, const float* __restrict__ W,
                       const float* __restrict__ bias,
                       float* __restrict__ U, float* __restrict__ V, int c0) {
    __shared__ float xt[16 * 128];
    const int tid = threadIdx.x;
    const int col = blockIdx.x * 64 + (tid & 63);
    const int gcol = c0 + col;
    const int r4 = tid >> 6;
    const int row0 = blockIdx.y * 16;
    for (int t = tid; t < 16 * 128; t += 256) xt[t] = (float)x[(size_t)row0 * 128 + t];
    __syncthreads();
    float u[4] = {0,0,0,0}, v[4] = {0,0,0,0};
    for (int c = 0; c < 128; ++c) {
        float wt = W[(size_t)c * 1024 + gcol];
        float wd = W[(size_t)(128 + c) * 1024 + gcol] - wt;
        #pragma unroll
        for (int rr = 0; rr < 4; ++rr) {
            float xv = xt[(r4 * 4 + rr) * 128 + c];
            u[rr] += xv * wt;
            v[rr] += xv * wd;
        }
    }
    float bb = bias[gcol];
    #pragma unroll
    for (int rr = 0; rr < 4; ++rr) {
        size_t o = (size_t)(row0 + r4 * 4 + rr) * 128 + col;
        U[o] = u[rr] + bb;
        V[o] = v[rr];
    }
}

// ============ layer-4 gather: k-reduce + BN stats + direct atomic max/min over N ============
// No Hmax/Hmin materialization; block pre-reduces NB rows then 1 atomic/channel.
__global__ void k_gather4(const int* __restrict__ idx,
                          const float* __restrict__ U, const float* __restrict__ V,
                          unsigned* __restrict__ Zmax, unsigned* __restrict__ Zmin,
                          double* __restrict__ ssum, double* __restrict__ sssq,
                          int c0, int NB) {
    const int tid = threadIdx.x;   // 0..127
    __shared__ int lidx[KK];
    double accs = 0.0, accq = 0.0;
    const int gn0 = blockIdx.x * NB;
    const int b = gn0 >> 10;       // NB | 1024 -> block stays in one batch
    float rmax = -3e38f, rmin = 3e38f;
    for (int r = 0; r < NB; ++r) {
        int gn = gn0 + r;
        __syncthreads();
        if (tid < KK) lidx[tid] = idx[(size_t)gn * KK + tid];
        __syncthreads();
        float u = U[(size_t)gn * 128 + tid];
        float vmax = -3e38f, vmin = 3e38f, vs = 0.f, vss = 0.f;
        for (int j = 0; j < KK; ++j) {
            int m = lidx[j];
            float vv = V[(size_t)((b << 10) + m) * 128 + tid];
            vmax = fmaxf(vmax, vv);
            vmin = fminf(vmin, vv);
            vs  += vv;
            vss += vv * vv;
        }
        accs += (double)((float)KK * u + vs);
        accq += (double)((float)KK * u * u + 2.f * u * vs + vss);
        rmax = fmaxf(rmax, u + vmax);
        rmin = fminf(rmin, u + vmin);
    }
    atomicAdd(&ssum[tid], accs);
    atomicAdd(&sssq[tid], accq);
    atomicMax(&Zmax[b * 1024 + c0 + tid], fkey(rmax));
    atomicMin(&Zmin[b * 1024 + c0 + tid], fkey(rmin));
}

__global__ void k_bnfin_f(const double* __restrict__ ssum, const double* __restrict__ sssq,
                          const float* __restrict__ g, const float* __restrict__ be,
                          float* __restrict__ S, float* __restrict__ T, int c0) {
    int gc = c0 + blockIdx.x * 64 + threadIdx.x;
    const double M = (double)BN * (double)KK;
    double mean = ssum[gc] / M;
    double var  = sssq[gc] / M - mean * mean;
    if (var < 0.0) var = 0.0;
    float s = (float)((double)g[gc] / sqrt(var + 1e-5));
    float t = (float)((double)be[gc] - mean * (double)s);
    S[gc] = s; T[gc] = t;
}

// ============ layer-4 finalize: z = relu(s*(s>=0?zmax:zmin)+t) ============
__global__ void k_zfin(const unsigned* __restrict__ Zmax, const unsigned* __restrict__ Zmin,
                       const float* __restrict__ S, const float* __restrict__ T,
                       float* __restrict__ z, int c0) {
    const int b = blockIdx.y;
    const int c = c0 + blockIdx.x * 64 + threadIdx.x;
    float s = S[c], t = T[c];
    float e = (s >= 0.f) ? funkey(Zmax[b * 1024 + c]) : funkey(Zmin[b * 1024 + c]);
    z[(size_t)b * 1024 + c] = fmaxf(s * e + t, 0.f);
}

// ============ FC head ============
__global__ void k_fc1(const float* __restrict__ z, const float* __restrict__ Wc1,
                      const float* __restrict__ bc1, float* __restrict__ a1) {
    int j = blockIdx.x * blockDim.x + threadIdx.x;
    if (j >= BB * 512) return;
    int b = j >> 9, jj = j & 511;
    const float* zr = z + (size_t)b * 1024;
    float acc = bc1[jj];
    for (int c = 0; c < 1024; ++c) acc += zr[c] * Wc1[(size_t)c * 512 + jj];
    a1[j] = fmaxf(acc, 0.f);
}

__global__ void k_fc2(const float* __restrict__ a1, const float* __restrict__ Wc2,
                      const float* __restrict__ bc2, float* __restrict__ out) {
    int j = blockIdx.x * blockDim.x + threadIdx.x;
    if (j >= BB * 40) return;
    int b = j / 40, jj = j % 40;
    const float* ar = a1 + (size_t)b * 512;
    float acc = bc2[jj];
    for (int c = 0; c < 512; ++c) acc += ar[c] * Wc2[(size_t)c * 40 + jj];
    out[j] = acc;
}

extern "C" void kernel_launch(void* const* d_in, const int* in_sizes, int n_in,
                              void* d_out, int out_size, void* d_ws, size_t ws_size,
                              hipStream_t stream) {
    const float* pos = (const float*)d_in[0];
    const float* Wc1 = (const float*)d_in[17];
    const float* bc1 = (const float*)d_in[18];
    const float* Wc2 = (const float*)d_in[19];
    const float* bc2 = (const float*)d_in[20];

    char* p = (char*)d_ws;
    auto alloc = [&](size_t bytes) -> void* {
        void* r = (void*)p;
        p += (bytes + 255) & ~(size_t)255;
        return r;
    };
    void*     bufA = alloc((size_t)BN * 64 * 8);    // U (fp64 L1-3 / fp32 L4 chunk)
    void*     bufB = alloc((size_t)BN * 64 * 8);    // V
    void*     bufC = alloc((size_t)BN * 64 * 8);    // Hmin (L1-3 only)
    double*   Ya   = (double*)alloc((size_t)BN * 64 * 8);
    double*   Yb   = (double*)alloc((size_t)BN * 128 * 8);
    double*   Xd   = (double*)alloc((size_t)BN * 3 * 8);
    double*   SQd  = (double*)alloc((size_t)BN * 8);
    int*      IDX  = (int*)   alloc((size_t)BN * KK * 4);
    double*   SSUM = (double*)alloc((size_t)4096 * 8);
    double*   SSSQ = (double*)alloc((size_t)4096 * 8);
    double*   Sd   = (double*)alloc((size_t)128 * 8);
    double*   Td   = (double*)alloc((size_t)128 * 8);
    float*    Sf   = (float*) alloc((size_t)1024 * 4);
    float*    Tf   = (float*) alloc((size_t)1024 * 4);
    unsigned* Zmax = (unsigned*)alloc((size_t)BB * 1024 * 4);
    unsigned* Zmin = (unsigned*)alloc((size_t)BB * 1024 * 4);
    float*    Z    = (float*) alloc((size_t)BB * 1024 * 4);
    float*    A1   = (float*) alloc((size_t)BB * 512 * 4);

    double* Ud = (double*)bufA; double* Vd = (double*)bufB; double* Hd = (double*)bufC;
    float*  Uf = (float*)bufA;  float*  Vf = (float*)bufB;

    hipMemsetAsync(SSUM, 0, 4096 * 8 * 2, stream);       // SSUM+SSSQ contiguous
    hipMemsetAsync(Zmax, 0x00, (size_t)BB * 1024 * 4, stream);
    hipMemsetAsync(Zmin, 0xFF, (size_t)BB * 1024 * 4, stream);

    k_cast3<<<(BN + 255) / 256, 256, 0, stream>>>(pos, Xd, SQd);

    // ---- Layer 1: C=3 -> 64 ----
    {
        const float* W = (const float*)d_in[1], *bs = (const float*)d_in[2];
        const float* g = (const float*)d_in[3], *be = (const float*)d_in[4];
        k_knn2<3, 64><<<dim3(NN / 4, BB), 256, 0, stream>>>(Xd, SQd, IDX);
        k_uv_d<3><<<BN / 16, 256, 0, stream>>>(Xd, W, bs, Ud, Vd, 64, 0);
        k_gather_d<<<BN / 8, 64, 0, stream>>>(IDX, Ud, Vd, Hd, SSUM, SSSQ, 8);
        k_bnfin_d<<<1, 64, 0, stream>>>(SSUM, SSSQ, g, be, Sd, Td, 0);
        k_apply_d<<<BN, 64, 0, stream>>>(Ud, Hd, Sd, Td, Ya, 64, 0);
        k_sqnorm_d<<<BN / 4, 256, 0, stream>>>(Ya, SQd, 64);
    }
    // ---- Layer 2: C=64 -> 64 ----
    {
        const float* W = (const float*)d_in[5], *bs = (const float*)d_in[6];
        const float* g = (const float*)d_in[7], *be = (const float*)d_in[8];
        k_knn2<64, 64><<<dim3(NN / 4, BB), 256, 0, stream>>>(Ya, SQd, IDX);
        k_uv_d<64><<<BN / 16, 256, 0, stream>>>(Ya, W, bs, Ud, Vd, 64, 0);
        k_gather_d<<<BN / 8, 64, 0, stream>>>(IDX, Ud, Vd, Hd, SSUM + 1024, SSSQ + 1024, 8);
        k_bnfin_d<<<1, 64, 0, stream>>>(SSUM + 1024, SSSQ + 1024, g, be, Sd, Td, 0);
        k_apply_d<<<BN, 64, 0, stream>>>(Ud, Hd, Sd, Td, Ya, 64, 0);
        k_sqnorm_d<<<BN / 4, 256, 0, stream>>>(Ya, SQd, 64);
    }
    // ---- Layer 3: C=64 -> 128, two 64-col chunks, Ya -> Yb ----
    {
        const float* W = (const float*)d_in[9], *bs = (const float*)d_in[10];
        const float* g = (const float*)d_in[11], *be = (const float*)d_in[12];
        k_knn2<64, 64><<<dim3(NN / 4, BB), 256, 0, stream>>>(Ya, SQd, IDX);
        for (int cc = 0; cc < 2; ++cc) {
            const int c0 = cc * 64;
            k_uv_d<64><<<BN / 16, 256, 0, stream>>>(Ya, W, bs, Ud, Vd, 128, c0);
            k_gather_d<<<BN / 8, 64, 0, stream>>>(IDX, Ud, Vd, Hd,
                                                  SSUM + 2048 + c0, SSSQ + 2048 + c0, 8);
            k_bnfin_d<<<1, 64, 0, stream>>>(SSUM + 2048, SSSQ + 2048, g, be, Sd, Td, c0);
            k_apply_d<<<BN, 64, 0, stream>>>(Ud, Hd, Sd, Td, Yb, 128, c0);
        }
        k_sqnorm_d<<<BN / 4, 256, 0, stream>>>(Yb, SQd, 128);
    }
    // ---- Layer 4: C=128 -> 1024, fp32, eight 128-col chunks, no H materialization ----
    {
        const float* W = (const float*)d_in[13], *bs = (const float*)d_in[14];
        const float* g = (const float*)d_in[15], *be = (const float*)d_in[16];
        k_knn2<128, 32><<<dim3(NN / 4, BB), 256, 0, stream>>>(Yb, SQd, IDX);
        for (int cc = 0; cc < 8; ++cc) {
            const int c0 = cc * 128;
            k_uv_f<<<dim3(2, BN / 16), 256, 0, stream>>>(Yb, W, bs, Uf, Vf, c0);
            k_gather4<<<BN / 8, 128, 0, stream>>>(IDX, Uf, Vf, Zmax, Zmin,
                                                  SSUM + 3072 + c0, SSSQ + 3072 + c0, c0, 8);
            k_bnfin_f<<<2, 64, 0, stream>>>(SSUM + 3072, SSSQ + 3072, g, be, Sf, Tf, c0);
            k_zfin<<<dim3(2, BB), 64, 0, stream>>>(Zmax, Zmin, Sf, Tf, Z, c0);
        }
    }

    k_fc1<<<(BB * 512 + 255) / 256, 256, 0, stream>>>(Z, Wc1, bc1, A1);
    k_fc2<<<(BB * 40 + 255) / 256, 256, 0, stream>>>(A1, Wc2, bc2, (float*)d_out);
}

// Round 5
// 3841.271 us; speedup vs baseline: 5.3238x; 5.3238x over previous
//
#include <hip/hip_runtime.h>
#include <hip/hip_bf16.h>

#define BB 16
#define NN 1024
#define BN (BB*NN)
#define KK 20

// monotone float <-> uint key for atomic max/min (handles negatives)
__device__ inline unsigned fkey(float x) {
    unsigned b = __float_as_uint(x);
    return (b & 0x80000000u) ? ~b : (b | 0x80000000u);
}
__device__ inline float funkey(unsigned k) {
    unsigned b = (k & 0x80000000u) ? (k ^ 0x80000000u) : ~k;
    return __uint_as_float(b);
}

// ============ cast pos -> double + row sqnorm ============
__global__ void k_cast3(const float* __restrict__ pos, double* __restrict__ xd,
                        double* __restrict__ sq) {
    int gn = blockIdx.x * blockDim.x + threadIdx.x;
    if (gn >= BN) return;
    double s = 0.0;
    #pragma unroll
    for (int c = 0; c < 3; ++c) {
        double v = (double)pos[gn * 3 + c];
        xd[gn * 3 + c] = v;
        s += v * v;
    }
    sq[gn] = s;
}

// ============ kNN v3: dot phase -> LDS d[4][1024]; selection in registers ============
// Block = 256 = 4 waves = 4 query rows. Dot phase: tile loop NOT unrolled
// (d lives in LDS, no compile-time index needed -> no hoisting/spill blowup).
// GRP = 64/TM lanes cooperate per candidate dot, combined via shfl_xor.
// Selection: wave loads its d-row into 16 regs (compile-time unrolled), then
// 20x (local argmin + 6-step butterfly), zero barriers. fp64 exact,
// +1e10 diagonal, lowest-index tie-break.
template<int C, int TM>
__global__ __launch_bounds__(256, 4) void k_knn3(const double* __restrict__ x,
                                                 const double* __restrict__ sq,
                                                 int* __restrict__ idx) {
    __shared__ double d[4 * NN];                              // 32 KB
    __shared__ double xt[(C > 3) ? TM * (C + 1) : 1];
    __shared__ double xn4[(C > 3) ? 4 * C : 1];
    const int tid = threadIdx.x, lane = tid & 63, w = tid >> 6;
    const int b = blockIdx.y;
    const int n0 = blockIdx.x * 4;
    const int n = n0 + w;
    const double* xb  = x + (size_t)b * NN * C;
    const double* sqb = sq + b * NN;
    const double sqn = sqb[n];

    if constexpr (C == 3) {
        const double q0 = xb[n * 3 + 0], q1 = xb[n * 3 + 1], q2 = xb[n * 3 + 2];
        #pragma unroll 1
        for (int g = 0; g < 16; ++g) {
            int m = g * 64 + lane;
            double dot = xb[m * 3 + 0] * q0 + xb[m * 3 + 1] * q1 + xb[m * 3 + 2] * q2;
            double dd = sqn + sqb[m] - 2.0 * dot;
            if (m == n) dd += 1e10;
            d[w * NN + m] = dd;
        }
    } else {
        const int ST  = C + 1;            // pad: break power-of-2 bank stride
        const int GRP = 64 / TM;          // lanes per dot
        const int CL  = C / GRP;          // c-chunk per lane
        for (int t = tid; t < 4 * C; t += 256) {
            int r = t / C, c = t - r * C;
            xn4[r * C + c] = xb[(size_t)(n0 + r) * C + c];
        }
        const int cand = lane & (TM - 1), sub = lane / TM;
        #pragma unroll 1
        for (int m0 = 0; m0 < NN; m0 += TM) {
            for (int t = tid; t < TM * C; t += 256) {
                int r = t / C, c = t - r * C;
                xt[r * ST + c] = xb[(size_t)m0 * C + t];
            }
            __syncthreads();                   // also covers first-iter xn4 visibility
            double part = 0.0;
            const double* xr = &xt[cand * ST + sub * CL];
            const double* xq = &xn4[w * C + sub * CL];
            #pragma unroll
            for (int cc = 0; cc < CL; ++cc) part += xr[cc] * xq[cc];
            #pragma unroll
            for (int msk = TM; msk < 64; msk <<= 1) part += __shfl_xor(part, msk, 64);
            int m = m0 + cand;
            double dd = sqn + sqb[m] - 2.0 * part;
            if (m == n) dd += 1e10;
            if (sub == 0) d[w * NN + m] = dd;
            __syncthreads();                   // xt reused next iteration
        }
    }

    // ---- selection: registers, barrier-free (wave owns its own d row) ----
    double dloc[16];
    #pragma unroll
    for (int j = 0; j < 16; ++j) dloc[j] = d[w * NN + j * 64 + lane];
    const size_t rowbase = (size_t)(b * NN + n) * KK;
    for (int it = 0; it < KK; ++it) {
        double bv = dloc[0]; int bj = 0;
        #pragma unroll
        for (int j = 1; j < 16; ++j)
            if (dloc[j] < bv) { bv = dloc[j]; bj = j; }
        int bm = bj * 64 + lane;
        #pragma unroll
        for (int off = 32; off > 0; off >>= 1) {
            double ov = __shfl_xor(bv, off, 64);
            int    om = __shfl_xor(bm, off, 64);
            if (ov < bv || (ov == bv && om < bm)) { bv = ov; bm = om; }
        }
        if (lane == 0) idx[rowbase + it] = bm;
        if ((bm & 63) == lane) {
            const int wj = bm >> 6;
            #pragma unroll
            for (int j = 0; j < 16; ++j)
                if (j == wj) dloc[j] = 1e300;
        }
    }
}

// ============ UV GEMM fp64, 64-column chunk ============
template<int C>
__global__ void k_uv_d(const double* __restrict__ x, const float* __restrict__ W,
                       const float* __restrict__ bias,
                       double* __restrict__ U, double* __restrict__ V,
                       int Cout, int c0) {
    __shared__ double xt[16 * C];
    const int tid = threadIdx.x;
    const int col = tid & 63;
    const int gcol = c0 + col;
    const int r4 = tid >> 6;
    const int row0 = blockIdx.x * 16;
    for (int t = tid; t < 16 * C; t += 256) xt[t] = x[(size_t)row0 * C + t];
    __syncthreads();
    double u[4] = {0,0,0,0}, v[4] = {0,0,0,0};
    for (int c = 0; c < C; ++c) {
        double wt = (double)W[(size_t)c * Cout + gcol];
        double wd = (double)W[(size_t)(C + c) * Cout + gcol] - wt;
        #pragma unroll
        for (int rr = 0; rr < 4; ++rr) {
            double xv = xt[(r4 * 4 + rr) * C + c];
            u[rr] += xv * wt;
            v[rr] += xv * wd;
        }
    }
    double bb = (double)bias[gcol];
    #pragma unroll
    for (int rr = 0; rr < 4; ++rr) {
        size_t o = (size_t)(row0 + r4 * 4 + rr) * 64 + col;
        U[o] = u[rr] + bb;
        V[o] = v[rr];
    }
}

// ============ gather fp64 (L1-3): max/min over k + BN stats ============
__global__ void k_gather_d(const int* __restrict__ idx,
                           double* __restrict__ U, const double* __restrict__ V,
                           double* __restrict__ Hmin,
                           double* __restrict__ ssum, double* __restrict__ sssq, int NB) {
    const int tid = threadIdx.x, CS = blockDim.x;
    __shared__ int lidx[KK];
    double accs = 0.0, accq = 0.0;
    const int gn0 = blockIdx.x * NB;
    for (int r = 0; r < NB; ++r) {
        int gn = gn0 + r;
        int b = gn >> 10;
        __syncthreads();
        if (tid < KK) lidx[tid] = idx[(size_t)gn * KK + tid];
        __syncthreads();
        double u = U[(size_t)gn * CS + tid];
        double vmax = -1e300, vmin = 1e300, vs = 0.0, vss = 0.0;
        for (int j = 0; j < KK; ++j) {
            int m = lidx[j];
            double vv = V[(size_t)((b << 10) + m) * CS + tid];
            vmax = fmax(vmax, vv);
            vmin = fmin(vmin, vv);
            vs  += vv;
            vss += vv * vv;
        }
        accs += (double)KK * u + vs;
        accq += (double)KK * u * u + 2.0 * u * vs + vss;
        U[(size_t)gn * CS + tid]    = u + vmax;
        Hmin[(size_t)gn * CS + tid] = u + vmin;
    }
    atomicAdd(&ssum[tid], accs);
    atomicAdd(&sssq[tid], accq);
}

// ============ BN finalize fp64 ============
__global__ void k_bnfin_d(const double* __restrict__ ssum, const double* __restrict__ sssq,
                          const float* __restrict__ g, const float* __restrict__ be,
                          double* __restrict__ S, double* __restrict__ T, int c0) {
    int gc = c0 + threadIdx.x;
    const double M = (double)BN * (double)KK;
    double mean = ssum[gc] / M;
    double var  = sssq[gc] / M - mean * mean;
    if (var < 0.0) var = 0.0;
    double s = (double)g[gc] / sqrt(var + 1e-5);
    double t = (double)be[gc] - mean * s;
    S[gc] = s; T[gc] = t;
}

// ============ apply fp64 chunk ============
__global__ void k_apply_d(const double* __restrict__ Hmax, const double* __restrict__ Hmin,
                          const double* __restrict__ S, const double* __restrict__ T,
                          double* __restrict__ y, int Cout, int c0) {
    const int gn = blockIdx.x, tid = threadIdx.x;
    double s = S[c0 + tid], t = T[c0 + tid];
    double h = (s >= 0.0) ? Hmax[(size_t)gn * 64 + tid] : Hmin[(size_t)gn * 64 + tid];
    y[(size_t)gn * Cout + c0 + tid] = fmax(s * h + t, 0.0);
}

// ============ row sqnorm fp64 ============
__global__ void k_sqnorm_d(const double* __restrict__ y, double* __restrict__ sq, int C) {
    const int row = blockIdx.x * 4 + (threadIdx.x >> 6);
    const int lane = threadIdx.x & 63;
    const double* yr = y + (size_t)row * C;
    double s = 0.0;
    for (int c = lane; c < C; c += 64) { double v = yr[c]; s += v * v; }
    for (int off = 32; off > 0; off >>= 1) s += __shfl_xor(s, off, 64);
    if (lane == 0) sq[row] = s;
}

// ============ layer-4 fp32: UV GEMM (CS=128 chunks) ============
__global__ void k_uv_f(const double* __restrict__ x, const float* __restrict__ W,
                       const float* __restrict__ bias,
                       float* __restrict__ U, float* __restrict__ V, int c0) {
    __shared__ float xt[16 * 128];
    const int tid = threadIdx.x;
    const int col = blockIdx.x * 64 + (tid & 63);
    const int gcol = c0 + col;
    const int r4 = tid >> 6;
    const int row0 = blockIdx.y * 16;
    for (int t = tid; t < 16 * 128; t += 256) xt[t] = (float)x[(size_t)row0 * 128 + t];
    __syncthreads();
    float u[4] = {0,0,0,0}, v[4] = {0,0,0,0};
    for (int c = 0; c < 128; ++c) {
        float wt = W[(size_t)c * 1024 + gcol];
        float wd = W[(size_t)(128 + c) * 1024 + gcol] - wt;
        #pragma unroll
        for (int rr = 0; rr < 4; ++rr) {
            float xv = xt[(r4 * 4 + rr) * 128 + c];
            u[rr] += xv * wt;
            v[rr] += xv * wd;
        }
    }
    float bb = bias[gcol];
    #pragma unroll
    for (int rr = 0; rr < 4; ++rr) {
        size_t o = (size_t)(row0 + r4 * 4 + rr) * 128 + col;
        U[o] = u[rr] + bb;
        V[o] = v[rr];
    }
}

// ============ layer-4 gather: k-reduce + BN stats + atomic max/min over N ============
__global__ void k_gather4(const int* __restrict__ idx,
                          const float* __restrict__ U, const float* __restrict__ V,
                          unsigned* __restrict__ Zmax, unsigned* __restrict__ Zmin,
                          double* __restrict__ ssum, double* __restrict__ sssq,
                          int c0, int NB) {
    const int tid = threadIdx.x;   // 0..127
    __shared__ int lidx[KK];
    double accs = 0.0, accq = 0.0;
    const int gn0 = blockIdx.x * NB;
    const int b = gn0 >> 10;       // NB | 1024 -> block stays in one batch
    float rmax = -3e38f, rmin = 3e38f;
    for (int r = 0; r < NB; ++r) {
        int gn = gn0 + r;
        __syncthreads();
        if (tid < KK) lidx[tid] = idx[(size_t)gn * KK + tid];
        __syncthreads();
        float u = U[(size_t)gn * 128 + tid];
        float vmax = -3e38f, vmin = 3e38f, vs = 0.f, vss = 0.f;
        for (int j = 0; j < KK; ++j) {
            int m = lidx[j];
            float vv = V[(size_t)((b << 10) + m) * 128 + tid];
            vmax = fmaxf(vmax, vv);
            vmin = fminf(vmin, vv);
            vs  += vv;
            vss += vv * vv;
        }
        accs += (double)((float)KK * u + vs);
        accq += (double)((float)KK * u * u + 2.f * u * vs + vss);
        rmax = fmaxf(rmax, u + vmax);
        rmin = fminf(rmin, u + vmin);
    }
    atomicAdd(&ssum[tid], accs);
    atomicAdd(&sssq[tid], accq);
    atomicMax(&Zmax[b * 1024 + c0 + tid], fkey(rmax));
    atomicMin(&Zmin[b * 1024 + c0 + tid], fkey(rmin));
}

__global__ void k_bnfin_f(const double* __restrict__ ssum, const double* __restrict__ sssq,
                          const float* __restrict__ g, const float* __restrict__ be,
                          float* __restrict__ S, float* __restrict__ T, int c0) {
    int gc = c0 + blockIdx.x * 64 + threadIdx.x;
    const double M = (double)BN * (double)KK;
    double mean = ssum[gc] / M;
    double var  = sssq[gc] / M - mean * mean;
    if (var < 0.0) var = 0.0;
    float s = (float)((double)g[gc] / sqrt(var + 1e-5));
    float t = (float)((double)be[gc] - mean * (double)s);
    S[gc] = s; T[gc] = t;
}

// ============ layer-4 finalize: z = relu(s*(s>=0?zmax:zmin)+t) ============
__global__ void k_zfin(const unsigned* __restrict__ Zmax, const unsigned* __restrict__ Zmin,
                       const float* __restrict__ S, const float* __restrict__ T,
                       float* __restrict__ z, int c0) {
    const int b = blockIdx.y;
    const int c = c0 + blockIdx.x * 64 + threadIdx.x;
    float s = S[c], t = T[c];
    float e = (s >= 0.f) ? funkey(Zmax[b * 1024 + c]) : funkey(Zmin[b * 1024 + c]);
    z[(size_t)b * 1024 + c] = fmaxf(s * e + t, 0.f);
}

// ============ FC head ============
__global__ void k_fc1(const float* __restrict__ z, const float* __restrict__ Wc1,
                      const float* __restrict__ bc1, float* __restrict__ a1) {
    int j = blockIdx.x * blockDim.x + threadIdx.x;
    if (j >= BB * 512) return;
    int b = j >> 9, jj = j & 511;
    const float* zr = z + (size_t)b * 1024;
    float acc = bc1[jj];
    for (int c = 0; c < 1024; ++c) acc += zr[c] * Wc1[(size_t)c * 512 + jj];
    a1[j] = fmaxf(acc, 0.f);
}

__global__ void k_fc2(const float* __restrict__ a1, const float* __restrict__ Wc2,
                      const float* __restrict__ bc2, float* __restrict__ out) {
    int j = blockIdx.x * blockDim.x + threadIdx.x;
    if (j >= BB * 40) return;
    int b = j / 40, jj = j % 40;
    const float* ar = a1 + (size_t)b * 512;
    float acc = bc2[jj];
    for (int c = 0; c < 512; ++c) acc += ar[c] * Wc2[(size_t)c * 40 + jj];
    out[j] = acc;
}

extern "C" void kernel_launch(void* const* d_in, const int* in_sizes, int n_in,
                              void* d_out, int out_size, void* d_ws, size_t ws_size,
                              hipStream_t stream) {
    const float* pos = (const float*)d_in[0];
    const float* Wc1 = (const float*)d_in[17];
    const float* bc1 = (const float*)d_in[18];
    const float* Wc2 = (const float*)d_in[19];
    const float* bc2 = (const float*)d_in[20];

    char* p = (char*)d_ws;
    auto alloc = [&](size_t bytes) -> void* {
        void* r = (void*)p;
        p += (bytes + 255) & ~(size_t)255;
        return r;
    };
    void*     bufA = alloc((size_t)BN * 64 * 8);    // U (fp64 L1-3 / fp32 L4 chunk)
    void*     bufB = alloc((size_t)BN * 64 * 8);    // V
    void*     bufC = alloc((size_t)BN * 64 * 8);    // Hmin (L1-3 only)
    double*   Ya   = (double*)alloc((size_t)BN * 64 * 8);
    double*   Yb   = (double*)alloc((size_t)BN * 128 * 8);
    double*   Xd   = (double*)alloc((size_t)BN * 3 * 8);
    double*   SQd  = (double*)alloc((size_t)BN * 8);
    int*      IDX  = (int*)   alloc((size_t)BN * KK * 4);
    double*   SSUM = (double*)alloc((size_t)4096 * 8);
    double*   SSSQ = (double*)alloc((size_t)4096 * 8);
    double*   Sd   = (double*)alloc((size_t)128 * 8);
    double*   Td   = (double*)alloc((size_t)128 * 8);
    float*    Sf   = (float*) alloc((size_t)1024 * 4);
    float*    Tf   = (float*) alloc((size_t)1024 * 4);
    unsigned* Zmax = (unsigned*)alloc((size_t)BB * 1024 * 4);
    unsigned* Zmin = (unsigned*)alloc((size_t)BB * 1024 * 4);
    float*    Z    = (float*) alloc((size_t)BB * 1024 * 4);
    float*    A1   = (float*) alloc((size_t)BB * 512 * 4);

    double* Ud = (double*)bufA; double* Vd = (double*)bufB; double* Hd = (double*)bufC;
    float*  Uf = (float*)bufA;  float*  Vf = (float*)bufB;

    hipMemsetAsync(SSUM, 0, 4096 * 8 * 2, stream);       // SSUM+SSSQ contiguous
    hipMemsetAsync(Zmax, 0x00, (size_t)BB * 1024 * 4, stream);
    hipMemsetAsync(Zmin, 0xFF, (size_t)BB * 1024 * 4, stream);

    k_cast3<<<(BN + 255) / 256, 256, 0, stream>>>(pos, Xd, SQd);

    // ---- Layer 1: C=3 -> 64 ----
    {
        const float* W = (const float*)d_in[1], *bs = (const float*)d_in[2];
        const float* g = (const float*)d_in[3], *be = (const float*)d_in[4];
        k_knn3<3, 64><<<dim3(NN / 4, BB), 256, 0, stream>>>(Xd, SQd, IDX);
        k_uv_d<3><<<BN / 16, 256, 0, stream>>>(Xd, W, bs, Ud, Vd, 64, 0);
        k_gather_d<<<BN / 8, 64, 0, stream>>>(IDX, Ud, Vd, Hd, SSUM, SSSQ, 8);
        k_bnfin_d<<<1, 64, 0, stream>>>(SSUM, SSSQ, g, be, Sd, Td, 0);
        k_apply_d<<<BN, 64, 0, stream>>>(Ud, Hd, Sd, Td, Ya, 64, 0);
        k_sqnorm_d<<<BN / 4, 256, 0, stream>>>(Ya, SQd, 64);
    }
    // ---- Layer 2: C=64 -> 64 ----
    {
        const float* W = (const float*)d_in[5], *bs = (const float*)d_in[6];
        const float* g = (const float*)d_in[7], *be = (const float*)d_in[8];
        k_knn3<64, 32><<<dim3(NN / 4, BB), 256, 0, stream>>>(Ya, SQd, IDX);
        k_uv_d<64><<<BN / 16, 256, 0, stream>>>(Ya, W, bs, Ud, Vd, 64, 0);
        k_gather_d<<<BN / 8, 64, 0, stream>>>(IDX, Ud, Vd, Hd, SSUM + 1024, SSSQ + 1024, 8);
        k_bnfin_d<<<1, 64, 0, stream>>>(SSUM + 1024, SSSQ + 1024, g, be, Sd, Td, 0);
        k_apply_d<<<BN, 64, 0, stream>>>(Ud, Hd, Sd, Td, Ya, 64, 0);
        k_sqnorm_d<<<BN / 4, 256, 0, stream>>>(Ya, SQd, 64);
    }
    // ---- Layer 3: C=64 -> 128, two 64-col chunks, Ya -> Yb ----
    {
        const float* W = (const float*)d_in[9], *bs = (const float*)d_in[10];
        const float* g = (const float*)d_in[11], *be = (const float*)d_in[12];
        k_knn3<64, 32><<<dim3(NN / 4, BB), 256, 0, stream>>>(Ya, SQd, IDX);
        for (int cc = 0; cc < 2; ++cc) {
            const int c0 = cc * 64;
            k_uv_d<64><<<BN / 16, 256, 0, stream>>>(Ya, W, bs, Ud, Vd, 128, c0);
            k_gather_d<<<BN / 8, 64, 0, stream>>>(IDX, Ud, Vd, Hd,
                                                  SSUM + 2048 + c0, SSSQ + 2048 + c0, 8);
            k_bnfin_d<<<1, 64, 0, stream>>>(SSUM + 2048, SSSQ + 2048, g, be, Sd, Td, c0);
            k_apply_d<<<BN, 64, 0, stream>>>(Ud, Hd, Sd, Td, Yb, 128, c0);
        }
        k_sqnorm_d<<<BN / 4, 256, 0, stream>>>(Yb, SQd, 128);
    }
    // ---- Layer 4: C=128 -> 1024, fp32, eight 128-col chunks, no H materialization ----
    {
        const float* W = (const float*)d_in[13], *bs = (const float*)d_in[14];
        const float* g = (const float*)d_in[15], *be = (const float*)d_in[16];
        k_knn3<128, 16><<<dim3(NN / 4, BB), 256, 0, stream>>>(Yb, SQd, IDX);
        for (int cc = 0; cc < 8; ++cc) {
            const int c0 = cc * 128;
            k_uv_f<<<dim3(2, BN / 16), 256, 0, stream>>>(Yb, W, bs, Uf, Vf, c0);
            k_gather4<<<BN / 8, 128, 0, stream>>>(IDX, Uf, Vf, Zmax, Zmin,
                                                  SSUM + 3072 + c0, SSSQ + 3072 + c0, c0, 8);
            k_bnfin_f<<<2, 64, 0, stream>>>(SSUM + 3072, SSSQ + 3072, g, be, Sf, Tf, c0);
            k_zfin<<<dim3(2, BB), 64, 0, stream>>>(Zmax, Zmin, Sf, Tf, Z, c0);
        }
    }

    k_fc1<<<(BB * 512 + 255) / 256, 256, 0, stream>>>(Z, Wc1, bc1, A1);
    k_fc2<<<(BB * 40 + 255) / 256, 256, 0, stream>>>(A1, Wc2, bc2, (float*)d_out);
}

// Round 6
// 3248.030 us; speedup vs baseline: 6.2961x; 1.1826x over previous
//
#include <hip/hip_runtime.h>
#include <hip/hip_bf16.h>

#define BB 16
#define NN 1024
#define BN (BB*NN)
#define KK 20
#define MARGIN 25   // fp32 prefilter width (>= KK + safety)

// monotone float <-> uint key for atomic max/min (handles negatives)
__device__ inline unsigned fkey(float x) {
    unsigned b = __float_as_uint(x);
    return (b & 0x80000000u) ? ~b : (b | 0x80000000u);
}
__device__ inline float funkey(unsigned k) {
    unsigned b = (k & 0x80000000u) ? (k ^ 0x80000000u) : ~k;
    return __uint_as_float(b);
}

// ============ cast pos -> double + row sqnorm (fp64 + fp32) ============
__global__ void k_cast3(const float* __restrict__ pos, double* __restrict__ xd,
                        double* __restrict__ sqd, float* __restrict__ sqf) {
    int gn = blockIdx.x * blockDim.x + threadIdx.x;
    if (gn >= BN) return;
    double s = 0.0;
    #pragma unroll
    for (int c = 0; c < 3; ++c) {
        double v = (double)pos[gn * 3 + c];
        xd[gn * 3 + c] = v;
        s += v * v;
    }
    sqd[gn] = s;
    sqf[gn] = (float)s;
}

// ============ prep: fp64 y -> fp32 copy + sqnorms (fp64 + fp32) ============
__global__ void k_prep(const double* __restrict__ y, float* __restrict__ yf,
                       double* __restrict__ sqd, float* __restrict__ sqf, int C) {
    const int row = blockIdx.x * 4 + (threadIdx.x >> 6);
    const int lane = threadIdx.x & 63;
    const double* yr = y + (size_t)row * C;
    float* yfr = yf + (size_t)row * C;
    double s = 0.0;
    for (int c = lane; c < C; c += 64) {
        double v = yr[c];
        s += v * v;
        yfr[c] = (float)v;
    }
    #pragma unroll
    for (int off = 32; off > 0; off >>= 1) s += __shfl_xor(s, off, 64);
    if (lane == 0) { sqd[row] = s; sqf[row] = (float)s; }
}

// ============ kNN v4: fp32 prefilter (top-MARGIN) + fp64 exact re-rank ============
// Block = 256 = 4 waves = 4 query rows. Phase 1: fp32 distances -> LDS d[4][1024]
// (tile loop not unrolled; +1-float pad -> free 2-way bank aliasing).
// Phase 2: per-wave barrier-free selection of MARGIN smallest (fp32, idx tie-break).
// Phase 3: wave cooperatively recomputes those MARGIN distances in fp64 (exact
// formula sqn+sqm-2*dot) and emits the true top-KK. Downstream consumes the SET.
template<int C, int TM>
__global__ __launch_bounds__(256, 4) void k_knn4(const float* __restrict__ xf,
                                                 const float* __restrict__ sqf,
                                                 const double* __restrict__ xd,
                                                 const double* __restrict__ sqd,
                                                 int* __restrict__ idx) {
    __shared__ float d[4 * NN];                        // 16 KB
    __shared__ float xt[(C > 3) ? TM * (C + 1) : 1];
    __shared__ float xn4[(C > 3) ? 4 * C : 1];
    __shared__ float sqs[NN];                          // 4 KB
    __shared__ int   picksS[4 * 32];
    const int tid = threadIdx.x, lane = tid & 63, w = tid >> 6;
    const int b = blockIdx.y;
    const int n0 = blockIdx.x * 4;
    const int n = n0 + w;
    const float* xb = xf + (size_t)b * NN * C;

    for (int t = tid; t < NN; t += 256) sqs[t] = sqf[b * NN + t];

    // ---- phase 1: fp32 distances ----
    if constexpr (C == 3) {
        __syncthreads();
        const float q0 = xb[n * 3 + 0], q1 = xb[n * 3 + 1], q2 = xb[n * 3 + 2];
        const float sqn = sqs[n];
        #pragma unroll 1
        for (int g = 0; g < 16; ++g) {
            int m = g * 64 + lane;
            float dot = xb[m * 3 + 0] * q0 + xb[m * 3 + 1] * q1 + xb[m * 3 + 2] * q2;
            float dd = sqn + sqs[m] - 2.f * dot;
            if (m == n) dd += 1e10f;
            d[w * NN + m] = dd;
        }
    } else {
        const int ST  = C + 1;            // +1 float pad -> 2-way aliasing (free)
        const int GRP = 64 / TM;          // lanes per candidate dot
        const int CL  = C / GRP;          // c-chunk per lane
        for (int t = tid; t < 4 * C; t += 256) xn4[t] = xb[(size_t)n0 * C + t];
        __syncthreads();
        const float sqn = sqs[n];
        const int cand = lane & (TM - 1), sub = lane / TM;
        #pragma unroll 1
        for (int m0 = 0; m0 < NN; m0 += TM) {
            for (int t4 = tid; t4 < TM * C / 4; t4 += 256) {
                float4 val = ((const float4*)(xb + (size_t)m0 * C))[t4];
                int flat = t4 * 4, r = flat / C, c = flat - r * C;
                float* dst = &xt[r * ST + c];
                dst[0] = val.x; dst[1] = val.y; dst[2] = val.z; dst[3] = val.w;
            }
            __syncthreads();
            float part = 0.f;
            const float* xr = &xt[cand * ST + sub * CL];
            const float* xq = &xn4[w * C + sub * CL];
            #pragma unroll
            for (int cc = 0; cc < CL; ++cc) part += xr[cc] * xq[cc];
            #pragma unroll
            for (int msk = TM; msk < 64; msk <<= 1) part += __shfl_xor(part, msk, 64);
            int m = m0 + cand;
            float dd = sqn + sqs[m] - 2.f * part;
            if (m == n) dd += 1e10f;
            if (sub == 0) d[w * NN + m] = dd;
            __syncthreads();
        }
    }

    // ---- phase 2: fp32 selection of MARGIN smallest (wave-private, no barriers) ----
    float dloc[16];
    #pragma unroll
    for (int j = 0; j < 16; ++j) dloc[j] = d[w * NN + j * 64 + lane];
    for (int it = 0; it < MARGIN; ++it) {
        float bv = dloc[0]; int bj = 0;
        #pragma unroll
        for (int j = 1; j < 16; ++j)
            if (dloc[j] < bv) { bv = dloc[j]; bj = j; }
        int bm = bj * 64 + lane;
        #pragma unroll
        for (int off = 32; off > 0; off >>= 1) {
            float ov = __shfl_xor(bv, off, 64);
            int   om = __shfl_xor(bm, off, 64);
            if (ov < bv || (ov == bv && om < bm)) { bv = ov; bm = om; }
        }
        if (lane == 0) picksS[w * 32 + it] = bm;
        if ((bm & 63) == lane) {
            const int wj = bm >> 6;
            #pragma unroll
            for (int j = 0; j < 16; ++j)
                if (j == wj) dloc[j] = 1e30f;
        }
    }

    // ---- phase 3: fp64 exact re-rank of the MARGIN candidates ----
    const double* xdb  = xd + (size_t)b * NN * C;
    const double* sqdb = sqd + b * NN;
    const double sqnD = sqdb[n];
    double qv0 = (lane < C) ? xdb[(size_t)n * C + lane] : 0.0;
    double qv1 = (C > 64) ? xdb[(size_t)n * C + lane + 64] : 0.0;
    double myv = 1e300; int mym = 0;
    for (int j = 0; j < MARGIN; ++j) {
        int m = picksS[w * 32 + j];
        double part = (lane < C) ? xdb[(size_t)m * C + lane] * qv0 : 0.0;
        if (C > 64) part += xdb[(size_t)m * C + lane + 64] * qv1;
        #pragma unroll
        for (int off = 32; off > 0; off >>= 1) part += __shfl_xor(part, off, 64);
        double dd = sqnD + sqdb[m] - 2.0 * part;
        if (lane == j) { myv = dd; mym = m; }
    }
    const size_t rowbase = (size_t)(b * NN + n) * KK;
    for (int it = 0; it < KK; ++it) {
        double bv = myv; int bm = mym;
        #pragma unroll
        for (int off = 32; off > 0; off >>= 1) {
            double ov = __shfl_xor(bv, off, 64);
            int    om = __shfl_xor(bm, off, 64);
            if (ov < bv || (ov == bv && om < bm)) { bv = ov; bm = om; }
        }
        if (lane == 0) idx[rowbase + it] = bm;
        if (mym == bm && myv == bv) myv = 1e300;
    }
}

// ============ UV GEMM fp64, 64-column chunk ============
template<int C>
__global__ void k_uv_d(const double* __restrict__ x, const float* __restrict__ W,
                       const float* __restrict__ bias,
                       double* __restrict__ U, double* __restrict__ V,
                       int Cout, int c0) {
    __shared__ double xt[16 * C];
    const int tid = threadIdx.x;
    const int col = tid & 63;
    const int gcol = c0 + col;
    const int r4 = tid >> 6;
    const int row0 = blockIdx.x * 16;
    for (int t = tid; t < 16 * C; t += 256) xt[t] = x[(size_t)row0 * C + t];
    __syncthreads();
    double u[4] = {0,0,0,0}, v[4] = {0,0,0,0};
    for (int c = 0; c < C; ++c) {
        double wt = (double)W[(size_t)c * Cout + gcol];
        double wd = (double)W[(size_t)(C + c) * Cout + gcol] - wt;
        #pragma unroll
        for (int rr = 0; rr < 4; ++rr) {
            double xv = xt[(r4 * 4 + rr) * C + c];
            u[rr] += xv * wt;
            v[rr] += xv * wd;
        }
    }
    double bb = (double)bias[gcol];
    #pragma unroll
    for (int rr = 0; rr < 4; ++rr) {
        size_t o = (size_t)(row0 + r4 * 4 + rr) * 64 + col;
        U[o] = u[rr] + bb;
        V[o] = v[rr];
    }
}

// ============ gather fp64 (L1-3): max/min over k + BN stats ============
__global__ void k_gather_d(const int* __restrict__ idx,
                           double* __restrict__ U, const double* __restrict__ V,
                           double* __restrict__ Hmin,
                           double* __restrict__ ssum, double* __restrict__ sssq, int NB) {
    const int tid = threadIdx.x, CS = blockDim.x;
    __shared__ int lidx[KK];
    double accs = 0.0, accq = 0.0;
    const int gn0 = blockIdx.x * NB;
    for (int r = 0; r < NB; ++r) {
        int gn = gn0 + r;
        int b = gn >> 10;
        __syncthreads();
        if (tid < KK) lidx[tid] = idx[(size_t)gn * KK + tid];
        __syncthreads();
        double u = U[(size_t)gn * CS + tid];
        double vmax = -1e300, vmin = 1e300, vs = 0.0, vss = 0.0;
        for (int j = 0; j < KK; ++j) {
            int m = lidx[j];
            double vv = V[(size_t)((b << 10) + m) * CS + tid];
            vmax = fmax(vmax, vv);
            vmin = fmin(vmin, vv);
            vs  += vv;
            vss += vv * vv;
        }
        accs += (double)KK * u + vs;
        accq += (double)KK * u * u + 2.0 * u * vs + vss;
        U[(size_t)gn * CS + tid]    = u + vmax;
        Hmin[(size_t)gn * CS + tid] = u + vmin;
    }
    atomicAdd(&ssum[tid], accs);
    atomicAdd(&sssq[tid], accq);
}

// ============ BN finalize fp64 ============
__global__ void k_bnfin_d(const double* __restrict__ ssum, const double* __restrict__ sssq,
                          const float* __restrict__ g, const float* __restrict__ be,
                          double* __restrict__ S, double* __restrict__ T, int c0) {
    int gc = c0 + threadIdx.x;
    const double M = (double)BN * (double)KK;
    double mean = ssum[gc] / M;
    double var  = sssq[gc] / M - mean * mean;
    if (var < 0.0) var = 0.0;
    double s = (double)g[gc] / sqrt(var + 1e-5);
    double t = (double)be[gc] - mean * s;
    S[gc] = s; T[gc] = t;
}

// ============ apply fp64 chunk ============
__global__ void k_apply_d(const double* __restrict__ Hmax, const double* __restrict__ Hmin,
                          const double* __restrict__ S, const double* __restrict__ T,
                          double* __restrict__ y, int Cout, int c0) {
    const int gn = blockIdx.x, tid = threadIdx.x;
    double s = S[c0 + tid], t = T[c0 + tid];
    double h = (s >= 0.0) ? Hmax[(size_t)gn * 64 + tid] : Hmin[(size_t)gn * 64 + tid];
    y[(size_t)gn * Cout + c0 + tid] = fmax(s * h + t, 0.0);
}

// ============ layer-4 fp32: UV GEMM (CS=128 chunks) ============
__global__ void k_uv_f(const double* __restrict__ x, const float* __restrict__ W,
                       const float* __restrict__ bias,
                       float* __restrict__ U, float* __restrict__ V, int c0) {
    __shared__ float xt[16 * 128];
    const int tid = threadIdx.x;
    const int col = blockIdx.x * 64 + (tid & 63);
    const int gcol = c0 + col;
    const int r4 = tid >> 6;
    const int row0 = blockIdx.y * 16;
    for (int t = tid; t < 16 * 128; t += 256) xt[t] = (float)x[(size_t)row0 * 128 + t];
    __syncthreads();
    float u[4] = {0,0,0,0}, v[4] = {0,0,0,0};
    for (int c = 0; c < 128; ++c) {
        float wt = W[(size_t)c * 1024 + gcol];
        float wd = W[(size_t)(128 + c) * 1024 + gcol] - wt;
        #pragma unroll
        for (int rr = 0; rr < 4; ++rr) {
            float xv = xt[(r4 * 4 + rr) * 128 + c];
            u[rr] += xv * wt;
            v[rr] += xv * wd;
        }
    }
    float bb = bias[gcol];
    #pragma unroll
    for (int rr = 0; rr < 4; ++rr) {
        size_t o = (size_t)(row0 + r4 * 4 + rr) * 128 + col;
        U[o] = u[rr] + bb;
        V[o] = v[rr];
    }
}

// ============ layer-4 gather: k-reduce + BN stats + atomic max/min over N ============
__global__ void k_gather4(const int* __restrict__ idx,
                          const float* __restrict__ U, const float* __restrict__ V,
                          unsigned* __restrict__ Zmax, unsigned* __restrict__ Zmin,
                          double* __restrict__ ssum, double* __restrict__ sssq,
                          int c0, int NB) {
    const int tid = threadIdx.x;   // 0..127
    __shared__ int lidx[KK];
    double accs = 0.0, accq = 0.0;
    const int gn0 = blockIdx.x * NB;
    const int b = gn0 >> 10;
    float rmax = -3e38f, rmin = 3e38f;
    for (int r = 0; r < NB; ++r) {
        int gn = gn0 + r;
        __syncthreads();
        if (tid < KK) lidx[tid] = idx[(size_t)gn * KK + tid];
        __syncthreads();
        float u = U[(size_t)gn * 128 + tid];
        float vmax = -3e38f, vmin = 3e38f, vs = 0.f, vss = 0.f;
        for (int j = 0; j < KK; ++j) {
            int m = lidx[j];
            float vv = V[(size_t)((b << 10) + m) * 128 + tid];
            vmax = fmaxf(vmax, vv);
            vmin = fminf(vmin, vv);
            vs  += vv;
            vss += vv * vv;
        }
        accs += (double)((float)KK * u + vs);
        accq += (double)((float)KK * u * u + 2.f * u * vs + vss);
        rmax = fmaxf(rmax, u + vmax);
        rmin = fminf(rmin, u + vmin);
    }
    atomicAdd(&ssum[tid], accs);
    atomicAdd(&sssq[tid], accq);
    atomicMax(&Zmax[b * 1024 + c0 + tid], fkey(rmax));
    atomicMin(&Zmin[b * 1024 + c0 + tid], fkey(rmin));
}

__global__ void k_bnfin_f(const double* __restrict__ ssum, const double* __restrict__ sssq,
                          const float* __restrict__ g, const float* __restrict__ be,
                          float* __restrict__ S, float* __restrict__ T, int c0) {
    int gc = c0 + blockIdx.x * 64 + threadIdx.x;
    const double M = (double)BN * (double)KK;
    double mean = ssum[gc] / M;
    double var  = sssq[gc] / M - mean * mean;
    if (var < 0.0) var = 0.0;
    float s = (float)((double)g[gc] / sqrt(var + 1e-5));
    float t = (float)((double)be[gc] - mean * (double)s);
    S[gc] = s; T[gc] = t;
}

// ============ layer-4 finalize (single launch, all 1024 cols) ============
__global__ void k_zfin(const unsigned* __restrict__ Zmax, const unsigned* __restrict__ Zmin,
                       const float* __restrict__ S, const float* __restrict__ T,
                       float* __restrict__ z) {
    const int b = blockIdx.y;
    const int c = blockIdx.x * 64 + threadIdx.x;
    float s = S[c], t = T[c];
    float e = (s >= 0.f) ? funkey(Zmax[b * 1024 + c]) : funkey(Zmin[b * 1024 + c]);
    z[(size_t)b * 1024 + c] = fmaxf(s * e + t, 0.f);
}

// ============ FC head ============
__global__ void k_fc1(const float* __restrict__ z, const float* __restrict__ Wc1,
                      const float* __restrict__ bc1, float* __restrict__ a1) {
    int j = blockIdx.x * blockDim.x + threadIdx.x;
    if (j >= BB * 512) return;
    int b = j >> 9, jj = j & 511;
    const float* zr = z + (size_t)b * 1024;
    float acc = bc1[jj];
    for (int c = 0; c < 1024; ++c) acc += zr[c] * Wc1[(size_t)c * 512 + jj];
    a1[j] = fmaxf(acc, 0.f);
}

__global__ void k_fc2(const float* __restrict__ a1, const float* __restrict__ Wc2,
                      const float* __restrict__ bc2, float* __restrict__ out) {
    int j = blockIdx.x * blockDim.x + threadIdx.x;
    if (j >= BB * 40) return;
    int b = j / 40, jj = j % 40;
    const float* ar = a1 + (size_t)b * 512;
    float acc = bc2[jj];
    for (int c = 0; c < 512; ++c) acc += ar[c] * Wc2[(size_t)c * 40 + jj];
    out[j] = acc;
}

extern "C" void kernel_launch(void* const* d_in, const int* in_sizes, int n_in,
                              void* d_out, int out_size, void* d_ws, size_t ws_size,
                              hipStream_t stream) {
    const float* pos = (const float*)d_in[0];
    const float* Wc1 = (const float*)d_in[17];
    const float* bc1 = (const float*)d_in[18];
    const float* Wc2 = (const float*)d_in[19];
    const float* bc2 = (const float*)d_in[20];

    char* p = (char*)d_ws;
    auto alloc = [&](size_t bytes) -> void* {
        void* r = (void*)p;
        p += (bytes + 255) & ~(size_t)255;
        return r;
    };
    void*     bufA = alloc((size_t)BN * 64 * 8);    // U (fp64 L1-3 / fp32 L4 chunk)
    void*     bufB = alloc((size_t)BN * 64 * 8);    // V
    void*     bufC = alloc((size_t)BN * 64 * 8);    // Hmin (L1-3) / Ybf fp32 (L4)
    double*   Ya   = (double*)alloc((size_t)BN * 64 * 8);
    double*   Yb   = (double*)alloc((size_t)BN * 128 * 8);
    float*    Yaf  = (float*) alloc((size_t)BN * 64 * 4);
    double*   Xd   = (double*)alloc((size_t)BN * 3 * 8);
    double*   SQd  = (double*)alloc((size_t)BN * 8);
    float*    SQf  = (float*) alloc((size_t)BN * 4);
    int*      IDX  = (int*)   alloc((size_t)BN * KK * 4);
    double*   SSUM = (double*)alloc((size_t)4096 * 8);
    double*   SSSQ = (double*)alloc((size_t)4096 * 8);
    double*   Sd   = (double*)alloc((size_t)128 * 8);
    double*   Td   = (double*)alloc((size_t)128 * 8);
    float*    Sf   = (float*) alloc((size_t)1024 * 4);
    float*    Tf   = (float*) alloc((size_t)1024 * 4);
    unsigned* Zmax = (unsigned*)alloc((size_t)BB * 1024 * 4);
    unsigned* Zmin = (unsigned*)alloc((size_t)BB * 1024 * 4);
    float*    Z    = (float*) alloc((size_t)BB * 1024 * 4);
    float*    A1   = (float*) alloc((size_t)BB * 512 * 4);
    // total ~= 55 MB

    double* Ud = (double*)bufA; double* Vd = (double*)bufB; double* Hd = (double*)bufC;
    float*  Uf = (float*)bufA;  float*  Vf = (float*)bufB;  float*  Ybf = (float*)bufC;

    hipMemsetAsync(SSUM, 0, 4096 * 8 * 2, stream);       // SSUM+SSSQ contiguous
    hipMemsetAsync(Zmax, 0x00, (size_t)BB * 1024 * 4, stream);
    hipMemsetAsync(Zmin, 0xFF, (size_t)BB * 1024 * 4, stream);

    k_cast3<<<(BN + 255) / 256, 256, 0, stream>>>(pos, Xd, SQd, SQf);

    // ---- Layer 1: C=3 -> 64 ----
    {
        const float* W = (const float*)d_in[1], *bs = (const float*)d_in[2];
        const float* g = (const float*)d_in[3], *be = (const float*)d_in[4];
        k_knn4<3, 64><<<dim3(NN / 4, BB), 256, 0, stream>>>(pos, SQf, Xd, SQd, IDX);
        k_uv_d<3><<<BN / 16, 256, 0, stream>>>(Xd, W, bs, Ud, Vd, 64, 0);
        k_gather_d<<<BN / 8, 64, 0, stream>>>(IDX, Ud, Vd, Hd, SSUM, SSSQ, 8);
        k_bnfin_d<<<1, 64, 0, stream>>>(SSUM, SSSQ, g, be, Sd, Td, 0);
        k_apply_d<<<BN, 64, 0, stream>>>(Ud, Hd, Sd, Td, Ya, 64, 0);
        k_prep<<<BN / 4, 256, 0, stream>>>(Ya, Yaf, SQd, SQf, 64);
    }
    // ---- Layer 2: C=64 -> 64 ----
    {
        const float* W = (const float*)d_in[5], *bs = (const float*)d_in[6];
        const float* g = (const float*)d_in[7], *be = (const float*)d_in[8];
        k_knn4<64, 64><<<dim3(NN / 4, BB), 256, 0, stream>>>(Yaf, SQf, Ya, SQd, IDX);
        k_uv_d<64><<<BN / 16, 256, 0, stream>>>(Ya, W, bs, Ud, Vd, 64, 0);
        k_gather_d<<<BN / 8, 64, 0, stream>>>(IDX, Ud, Vd, Hd, SSUM + 1024, SSSQ + 1024, 8);
        k_bnfin_d<<<1, 64, 0, stream>>>(SSUM + 1024, SSSQ + 1024, g, be, Sd, Td, 0);
        k_apply_d<<<BN, 64, 0, stream>>>(Ud, Hd, Sd, Td, Ya, 64, 0);
        k_prep<<<BN / 4, 256, 0, stream>>>(Ya, Yaf, SQd, SQf, 64);
    }
    // ---- Layer 3: C=64 -> 128, two 64-col chunks, Ya -> Yb ----
    {
        const float* W = (const float*)d_in[9], *bs = (const float*)d_in[10];
        const float* g = (const float*)d_in[11], *be = (const float*)d_in[12];
        k_knn4<64, 64><<<dim3(NN / 4, BB), 256, 0, stream>>>(Yaf, SQf, Ya, SQd, IDX);
        for (int cc = 0; cc < 2; ++cc) {
            const int c0 = cc * 64;
            k_uv_d<64><<<BN / 16, 256, 0, stream>>>(Ya, W, bs, Ud, Vd, 128, c0);
            k_gather_d<<<BN / 8, 64, 0, stream>>>(IDX, Ud, Vd, Hd,
                                                  SSUM + 2048 + c0, SSSQ + 2048 + c0, 8);
            k_bnfin_d<<<1, 64, 0, stream>>>(SSUM + 2048, SSSQ + 2048, g, be, Sd, Td, c0);
            k_apply_d<<<BN, 64, 0, stream>>>(Ud, Hd, Sd, Td, Yb, 128, c0);
        }
        k_prep<<<BN / 4, 256, 0, stream>>>(Yb, Ybf, SQd, SQf, 128);   // Ybf = bufC (Hd dead)
    }
    // ---- Layer 4: C=128 -> 1024, fp32, eight 128-col chunks ----
    {
        const float* W = (const float*)d_in[13], *bs = (const float*)d_in[14];
        const float* g = (const float*)d_in[15], *be = (const float*)d_in[16];
        k_knn4<128, 32><<<dim3(NN / 4, BB), 256, 0, stream>>>(Ybf, SQf, Yb, SQd, IDX);
        for (int cc = 0; cc < 8; ++cc) {
            const int c0 = cc * 128;
            k_uv_f<<<dim3(2, BN / 16), 256, 0, stream>>>(Yb, W, bs, Uf, Vf, c0);
            k_gather4<<<BN / 8, 128, 0, stream>>>(IDX, Uf, Vf, Zmax, Zmin,
                                                  SSUM + 3072 + c0, SSSQ + 3072 + c0, c0, 8);
            k_bnfin_f<<<2, 64, 0, stream>>>(SSUM + 3072, SSSQ + 3072, g, be, Sf, Tf, c0);
        }
        k_zfin<<<dim3(16, BB), 64, 0, stream>>>(Zmax, Zmin, Sf, Tf, Z);
    }

    k_fc1<<<(BB * 512 + 255) / 256, 256, 0, stream>>>(Z, Wc1, bc1, A1);
    k_fc2<<<(BB * 40 + 255) / 256, 256, 0, stream>>>(A1, Wc2, bc2, (float*)d_out);
}